// Round 1
// baseline (290.392 us; speedup 1.0000x reference)
//
#include <hip/hip_runtime.h>
#include <hip/hip_bf16.h>
#include <cstdint>
#include <cstddef>

typedef unsigned short u16;
typedef short s8v __attribute__((ext_vector_type(8)));
typedef float f4v __attribute__((ext_vector_type(4)));

#define SEQ   2048
#define BSZ   2
#define HID   1024
#define NH    16
#define DH    64
#define MROWS (BSZ*SEQ)

// f32 -> bf16 round-to-nearest-even (bit trick, handles sign/inf correctly)
__device__ __forceinline__ u16 f2b(float x) {
  union { float f; uint32_t u; } c; c.f = x;
  uint32_t r = (c.u + 0x7fffu + ((c.u >> 16) & 1u)) >> 16;
  return (u16)r;
}

__device__ __forceinline__ f4v mfma16(s8v a, s8v b, f4v c) {
  return __builtin_amdgcn_mfma_f32_16x16x32_bf16(a, b, c, 0, 0, 0);
}

typedef __attribute__((address_space(1))) const void gas_void;
typedef __attribute__((address_space(3))) void las_void;
__device__ __forceinline__ void gload_lds16(const void* g, void* l) {
  __builtin_amdgcn_global_load_lds((gas_void*)g, (las_void*)l, 16, 0, 0);
}

// ---------------- f32 -> bf16 conversion (5 arrays fused) ----------------
__global__ __launch_bounds__(256) void cvt5(
    const float* __restrict__ s0, const float* __restrict__ s1,
    const float* __restrict__ s2, const float* __restrict__ s3,
    const float* __restrict__ s4,
    u16* __restrict__ d0, u16* __restrict__ d1, u16* __restrict__ d2,
    u16* __restrict__ d3, u16* __restrict__ d4)
{
  const float* s; u16* d; int n;
  switch (blockIdx.y) {
    case 0:  s = s0; d = d0; n = MROWS*HID; break;
    case 1:  s = s1; d = d1; n = HID*HID;   break;
    case 2:  s = s2; d = d2; n = HID*HID;   break;
    case 3:  s = s3; d = d3; n = HID*HID;   break;
    default: s = s4; d = d4; n = HID*HID;   break;
  }
  const int n8 = n >> 3;
  const int stride = gridDim.x * blockDim.x;
  for (int i = blockIdx.x * blockDim.x + threadIdx.x; i < n8; i += stride) {
    const float4* p = (const float4*)s + (size_t)i * 2;
    float4 a = p[0], b = p[1];
    s8v ov;
    ov[0] = (short)f2b(a.x); ov[1] = (short)f2b(a.y);
    ov[2] = (short)f2b(a.z); ov[3] = (short)f2b(a.w);
    ov[4] = (short)f2b(b.x); ov[5] = (short)f2b(b.y);
    ov[6] = (short)f2b(b.z); ov[7] = (short)f2b(b.w);
    ((s8v*)d)[i] = ov;
  }
}

// ---------------- GEMM: C[M,N] = A[M,K] * B[N,K]^T + bias ----------------
// m97 structure: 128x128 tile, BK=32, 4 waves (each a 64x64 quadrant),
// global_load_lds width-16 staging, 16x16x32 bf16 MFMA.
template <bool OUTF32>
__global__ __launch_bounds__(256) void gemm_bt(
    const u16* __restrict__ A,
    const u16* __restrict__ B0, const u16* __restrict__ B1, const u16* __restrict__ B2,
    const float* __restrict__ bias0, const float* __restrict__ bias1, const float* __restrict__ bias2,
    void* C0, void* C1, void* C2,
    const int Ksz, const int Nsz)
{
  const u16* Bp; const float* bias; void* Cp;
  if (blockIdx.z == 0)      { Bp = B0; bias = bias0; Cp = C0; }
  else if (blockIdx.z == 1) { Bp = B1; bias = bias1; Cp = C1; }
  else                      { Bp = B2; bias = bias2; Cp = C2; }

  __shared__ __align__(16) u16 As[128 * 32];
  __shared__ __align__(16) u16 Bs[128 * 32];

  const int t  = threadIdx.x;
  const int w  = t >> 6;
  const int l  = t & 63;
  const int lr = l & 15;
  const int lg = l >> 4;
  const int wr = w >> 1;
  const int wc = w & 1;

  const int bm = blockIdx.x, bn = blockIdx.y;

  const int srow = t >> 2;          // 0..63
  const int scol = (t & 3) * 8;     // 0,8,16,24

  const u16* gA = A  + (size_t)(bm * 128 + srow) * Ksz + scol;
  const u16* gB = Bp + (size_t)(bn * 128 + srow) * Ksz + scol;
  const size_t half = (size_t)64 * Ksz;

  const f4v fzero = {0.f, 0.f, 0.f, 0.f};
  f4v acc[4][4];
#pragma unroll
  for (int m = 0; m < 4; ++m)
#pragma unroll
    for (int n = 0; n < 4; ++n) acc[m][n] = fzero;

  const int nk = Ksz >> 5;
  for (int kt = 0; kt < nk; ++kt) {
    if (kt) __syncthreads();
    gload_lds16(gA,        &As[t * 8]);
    gload_lds16(gA + half, &As[2048 + t * 8]);
    gload_lds16(gB,        &Bs[t * 8]);
    gload_lds16(gB + half, &Bs[2048 + t * 8]);
    gA += 32; gB += 32;
    __syncthreads();

    s8v af[4], bfr[4];
#pragma unroll
    for (int m = 0; m < 4; ++m)
      af[m] = *(const s8v*)&As[(wr * 64 + m * 16 + lr) * 32 + lg * 8];
#pragma unroll
    for (int n = 0; n < 4; ++n)
      bfr[n] = *(const s8v*)&Bs[(wc * 64 + n * 16 + lr) * 32 + lg * 8];
#pragma unroll
    for (int m = 0; m < 4; ++m)
#pragma unroll
      for (int n = 0; n < 4; ++n)
        acc[m][n] = mfma16(af[m], bfr[n], acc[m][n]);
  }

  // epilogue: C/D layout col = lane&15, row = (lane>>4)*4 + reg
#pragma unroll
  for (int n = 0; n < 4; ++n) {
    const int col = bn * 128 + wc * 64 + n * 16 + lr;
    const float bv = bias[col];
#pragma unroll
    for (int m = 0; m < 4; ++m) {
#pragma unroll
      for (int r = 0; r < 4; ++r) {
        const int row = bm * 128 + wr * 64 + m * 16 + lg * 4 + r;
        const float val = acc[m][n][r] + bv;
        if (OUTF32) ((float*)Cp)[(size_t)row * Nsz + col] = val;
        else        ((u16*)Cp)[(size_t)row * Nsz + col] = f2b(val);
      }
    }
  }
}

// ---------------- fused causal attention ----------------
// grid (SEQ/64, NH, BSZ), 256 threads = 4 waves, each wave 16 q-rows.
// KV tiles of 32; K staged row-major via global_load_lds, V staged transposed.
__global__ __launch_bounds__(256) void attn_fused(
    const u16* __restrict__ Qm, const u16* __restrict__ Km,
    const u16* __restrict__ Vm, u16* __restrict__ Om)
{
  __shared__ __align__(16) u16 Ks[32 * 64];
  __shared__ __align__(16) u16 Vt[64 * 32];   // transposed: Vt[d][kv]
  __shared__ __align__(16) u16 Ps[4 * 16 * 32];

  const int qt = blockIdx.x;
  const int h  = blockIdx.y;
  const int b  = blockIdx.z;
  const int t  = threadIdx.x;
  const int w  = t >> 6;
  const int l  = t & 63;
  const int lr = l & 15;
  const int lg = l >> 4;

  const int qr0    = qt * 64 + w * 16;
  const int q_last = qr0 + 15;

  const u16* Qb = Qm + (size_t)(b * SEQ) * HID + h * DH;
  const u16* Kb = Km + (size_t)(b * SEQ) * HID + h * DH;
  const u16* Vb = Vm + (size_t)(b * SEQ) * HID + h * DH;

  // Q fragments hoisted for the whole kernel (paired k-convention with K reads)
  s8v aq0 = *(const s8v*)(Qb + (size_t)(qr0 + lr) * HID + lg * 8);
  s8v aq1 = *(const s8v*)(Qb + (size_t)(qr0 + lr) * HID + 32 + lg * 8);

  const f4v fzero = {0.f, 0.f, 0.f, 0.f};
  f4v o0 = fzero, o1 = fzero, o2 = fzero, o3 = fzero;
  float mrow[4] = {-1e30f, -1e30f, -1e30f, -1e30f};
  float lrow[4] = {0.f, 0.f, 0.f, 0.f};

  const int ktmax = 2 * qt + 1;
  const int krow = t >> 3;        // 0..31
  const int kcol = (t & 7) * 8;   // 0..56

  for (int kt = 0; kt <= ktmax; ++kt) {
    __syncthreads();
    // stage K tile [32][64] linearly
    gload_lds16(Kb + (size_t)(kt * 32 + krow) * HID + kcol, &Ks[t * 8]);
    // stage V transposed
    {
      s8v vv = *(const s8v*)(Vb + (size_t)(kt * 32 + krow) * HID + kcol);
#pragma unroll
      for (int j = 0; j < 8; ++j) Vt[(kcol + j) * 32 + krow] = (u16)vv[j];
    }
    __syncthreads();

    if (kt * 32 <= q_last) {   // wave-uniform skip of fully-masked tiles
      // S = Q K^T  (rows q, cols kv)
      f4v s0 = fzero, s1 = fzero;
      {
        s8v bk00 = *(const s8v*)&Ks[(0 * 16 + lr) * 64 + lg * 8];
        s8v bk01 = *(const s8v*)&Ks[(0 * 16 + lr) * 64 + 32 + lg * 8];
        s0 = mfma16(aq0, bk00, s0);
        s0 = mfma16(aq1, bk01, s0);
        s8v bk10 = *(const s8v*)&Ks[(1 * 16 + lr) * 64 + lg * 8];
        s8v bk11 = *(const s8v*)&Ks[(1 * 16 + lr) * 64 + 32 + lg * 8];
        s1 = mfma16(aq0, bk10, s1);
        s1 = mfma16(aq1, bk11, s1);
      }
      const bool need_mask = (kt * 32 + 31) > qr0;
#pragma unroll
      for (int r = 0; r < 4; ++r) {
        float v0 = s0[r] * 0.125f;
        float v1 = s1[r] * 0.125f;
        if (need_mask) {
          const int q = qr0 + lg * 4 + r;
          if (kt * 32 + lr > q)      v0 = -1e30f;
          if (kt * 32 + 16 + lr > q) v1 = -1e30f;
        }
        s0[r] = v0; s1[r] = v1;
      }
      // row max over the 16 lanes holding this row's columns
      float tm[4];
#pragma unroll
      for (int r = 0; r < 4; ++r) tm[r] = fmaxf(s0[r], s1[r]);
#pragma unroll
      for (int msk = 1; msk < 16; msk <<= 1) {
#pragma unroll
        for (int r = 0; r < 4; ++r) tm[r] = fmaxf(tm[r], __shfl_xor(tm[r], msk, 64));
      }
      float resc[4];
#pragma unroll
      for (int r = 0; r < 4; ++r) {
        const float mn = fmaxf(mrow[r], tm[r]);
        resc[r] = __expf(mrow[r] - mn);
        mrow[r] = mn;
      }
#pragma unroll
      for (int r = 0; r < 4; ++r) {
        s0[r] = __expf(s0[r] - mrow[r]);
        s1[r] = __expf(s1[r] - mrow[r]);
      }
      float ps[4];
#pragma unroll
      for (int r = 0; r < 4; ++r) ps[r] = s0[r] + s1[r];
#pragma unroll
      for (int msk = 1; msk < 16; msk <<= 1) {
#pragma unroll
        for (int r = 0; r < 4; ++r) ps[r] += __shfl_xor(ps[r], msk, 64);
      }
#pragma unroll
      for (int r = 0; r < 4; ++r) lrow[r] = lrow[r] * resc[r] + ps[r];
#pragma unroll
      for (int r = 0; r < 4; ++r) {
        o0[r] *= resc[r]; o1[r] *= resc[r]; o2[r] *= resc[r]; o3[r] *= resc[r];
      }
      // P -> LDS (true (q,kv) positions), then read back as MFMA A-fragment
      u16* Pw = &Ps[w * 512];
#pragma unroll
      for (int r = 0; r < 4; ++r) {
        Pw[(lg * 4 + r) * 32 + lr]      = f2b(s0[r]);
        Pw[(lg * 4 + r) * 32 + 16 + lr] = f2b(s1[r]);
      }
      asm volatile("s_waitcnt lgkmcnt(0)" ::: "memory");  // wave-local LDS RAW
      s8v ap  = *(const s8v*)&Pw[lr * 32 + lg * 8];
      s8v bv0 = *(const s8v*)&Vt[(0 * 16 + lr) * 32 + lg * 8];
      s8v bv1 = *(const s8v*)&Vt[(1 * 16 + lr) * 32 + lg * 8];
      s8v bv2 = *(const s8v*)&Vt[(2 * 16 + lr) * 32 + lg * 8];
      s8v bv3 = *(const s8v*)&Vt[(3 * 16 + lr) * 32 + lg * 8];
      o0 = mfma16(ap, bv0, o0);
      o1 = mfma16(ap, bv1, o1);
      o2 = mfma16(ap, bv2, o2);
      o3 = mfma16(ap, bv3, o3);
    }
  }

  // epilogue: normalize and store bf16 att
#pragma unroll
  for (int r = 0; r < 4; ++r) {
    const int q = qr0 + lg * 4 + r;
    u16* orow = Om + (size_t)(b * SEQ + q) * HID + h * DH;
    const float inv = 1.0f / lrow[r];
    orow[0 * 16 + lr] = f2b(o0[r] * inv);
    orow[1 * 16 + lr] = f2b(o1[r] * inv);
    orow[2 * 16 + lr] = f2b(o2[r] * inv);
    orow[3 * 16 + lr] = f2b(o3[r] * inv);
  }
}

// ---------------- launch ----------------
extern "C" void kernel_launch(void* const* d_in, const int* in_sizes, int n_in,
                              void* d_out, int out_size, void* d_ws, size_t ws_size,
                              hipStream_t stream) {
  const float* x  = (const float*)d_in[0];
  const float* Wq = (const float*)d_in[1];
  const float* bq = (const float*)d_in[2];
  const float* Wk = (const float*)d_in[3];
  const float* bk = (const float*)d_in[4];
  const float* Wv = (const float*)d_in[5];
  const float* bv = (const float*)d_in[6];
  const float* Wm = (const float*)d_in[7];
  const float* bm = (const float*)d_in[8];
  float* out = (float*)d_out;

  u16* xb  = (u16*)d_ws;
  u16* Wqb = xb  + (size_t)MROWS * HID;
  u16* Wkb = Wqb + (size_t)HID * HID;
  u16* Wvb = Wkb + (size_t)HID * HID;
  u16* Wmb = Wvb + (size_t)HID * HID;
  u16* Qm  = Wmb + (size_t)HID * HID;
  u16* Km  = Qm  + (size_t)MROWS * HID;
  u16* Vm  = Km  + (size_t)MROWS * HID;
  u16* att = Vm  + (size_t)MROWS * HID;

  cvt5<<<dim3(512, 5, 1), 256, 0, stream>>>(x, Wq, Wk, Wv, Wm, xb, Wqb, Wkb, Wvb, Wmb);
  gemm_bt<false><<<dim3(32, 8, 3), 256, 0, stream>>>(
      xb, Wqb, Wkb, Wvb, bq, bk, bv, Qm, Km, Vm, HID, HID);
  attn_fused<<<dim3(SEQ / 64, NH, BSZ), 256, 0, stream>>>(Qm, Km, Vm, att);
  gemm_bt<true><<<dim3(32, 8, 1), 256, 0, stream>>>(
      att, Wmb, Wmb, Wmb, bm, bm, bm, out, out, out, HID, HID);
}

// Round 2
// 169.968 us; speedup vs baseline: 1.7085x; 1.7085x over previous
//
#include <hip/hip_runtime.h>
#include <hip/hip_bf16.h>
#include <cstdint>
#include <cstddef>

typedef unsigned short u16;
typedef short s8v __attribute__((ext_vector_type(8)));
typedef float f4v __attribute__((ext_vector_type(4)));

#define SEQ   2048
#define BSZ   2
#define HID   1024
#define NH    16
#define DH    64
#define MROWS (BSZ*SEQ)
#define PSTR  40   // P LDS row stride in u16 (80 B: 16B-aligned reads, bank-spread)

// f32 -> bf16 round-to-nearest-even
__device__ __forceinline__ u16 f2b(float x) {
  union { float f; uint32_t u; } c; c.f = x;
  uint32_t r = (c.u + 0x7fffu + ((c.u >> 16) & 1u)) >> 16;
  return (u16)r;
}

__device__ __forceinline__ f4v mfma16(s8v a, s8v b, f4v c) {
  return __builtin_amdgcn_mfma_f32_16x16x32_bf16(a, b, c, 0, 0, 0);
}

__device__ __forceinline__ float fexp2(float x) {
#if __has_builtin(__builtin_amdgcn_exp2f)
  return __builtin_amdgcn_exp2f(x);
#else
  return exp2f(x);
#endif
}

typedef __attribute__((address_space(1))) const void gas_void;
typedef __attribute__((address_space(3))) void las_void;
__device__ __forceinline__ void gload_lds16(const void* g, void* l) {
  __builtin_amdgcn_global_load_lds((gas_void*)g, (las_void*)l, 16, 0, 0);
}

// ---------------- f32 -> bf16 conversion (5 arrays fused) ----------------
__global__ __launch_bounds__(256) void cvt5(
    const float* __restrict__ s0, const float* __restrict__ s1,
    const float* __restrict__ s2, const float* __restrict__ s3,
    const float* __restrict__ s4,
    u16* __restrict__ d0, u16* __restrict__ d1, u16* __restrict__ d2,
    u16* __restrict__ d3, u16* __restrict__ d4)
{
  const float* s; u16* d; int n;
  switch (blockIdx.y) {
    case 0:  s = s0; d = d0; n = MROWS*HID; break;
    case 1:  s = s1; d = d1; n = HID*HID;   break;
    case 2:  s = s2; d = d2; n = HID*HID;   break;
    case 3:  s = s3; d = d3; n = HID*HID;   break;
    default: s = s4; d = d4; n = HID*HID;   break;
  }
  const int n8 = n >> 3;
  const int stride = gridDim.x * blockDim.x;
  for (int i = blockIdx.x * blockDim.x + threadIdx.x; i < n8; i += stride) {
    const float4* p = (const float4*)s + (size_t)i * 2;
    float4 a = p[0], b = p[1];
    s8v ov;
    ov[0] = (short)f2b(a.x); ov[1] = (short)f2b(a.y);
    ov[2] = (short)f2b(a.z); ov[3] = (short)f2b(a.w);
    ov[4] = (short)f2b(b.x); ov[5] = (short)f2b(b.y);
    ov[6] = (short)f2b(b.z); ov[7] = (short)f2b(b.w);
    ((s8v*)d)[i] = ov;
  }
}

// ---------------- GEMM: C[M,N] = A[M,K] * B[N,K]^T + bias ----------------
// 128x128 tile, BK=32, 4 waves, global_load_lds width-16, 16x16x32 bf16 MFMA.
// TRV: blockIdx.z==2 output is stored TRANSPOSED per batch:
//      Vt[(b*HID + col)*SEQ + s]  (s = row within batch)
template <bool OUTF32, bool TRV>
__global__ __launch_bounds__(256) void gemm_bt(
    const u16* __restrict__ A,
    const u16* __restrict__ B0, const u16* __restrict__ B1, const u16* __restrict__ B2,
    const float* __restrict__ bias0, const float* __restrict__ bias1, const float* __restrict__ bias2,
    void* C0, void* C1, void* C2,
    const int Ksz, const int Nsz)
{
  const u16* Bp; const float* bias; void* Cp;
  if (blockIdx.z == 0)      { Bp = B0; bias = bias0; Cp = C0; }
  else if (blockIdx.z == 1) { Bp = B1; bias = bias1; Cp = C1; }
  else                      { Bp = B2; bias = bias2; Cp = C2; }

  __shared__ __align__(16) u16 As[128 * 32];
  __shared__ __align__(16) u16 Bs[128 * 32];

  const int t  = threadIdx.x;
  const int w  = t >> 6;
  const int l  = t & 63;
  const int lr = l & 15;
  const int lg = l >> 4;
  const int wr = w >> 1;
  const int wc = w & 1;

  const int bm = blockIdx.x, bn = blockIdx.y;

  const int srow = t >> 2;
  const int scol = (t & 3) * 8;

  const u16* gA = A  + (size_t)(bm * 128 + srow) * Ksz + scol;
  const u16* gB = Bp + (size_t)(bn * 128 + srow) * Ksz + scol;
  const size_t half = (size_t)64 * Ksz;

  const f4v fzero = {0.f, 0.f, 0.f, 0.f};
  f4v acc[4][4];
#pragma unroll
  for (int m = 0; m < 4; ++m)
#pragma unroll
    for (int n = 0; n < 4; ++n) acc[m][n] = fzero;

  const int nk = Ksz >> 5;
  for (int kt = 0; kt < nk; ++kt) {
    if (kt) __syncthreads();
    gload_lds16(gA,        &As[t * 8]);
    gload_lds16(gA + half, &As[2048 + t * 8]);
    gload_lds16(gB,        &Bs[t * 8]);
    gload_lds16(gB + half, &Bs[2048 + t * 8]);
    gA += 32; gB += 32;
    __syncthreads();

    s8v af[4], bfr[4];
#pragma unroll
    for (int m = 0; m < 4; ++m)
      af[m] = *(const s8v*)&As[(wr * 64 + m * 16 + lr) * 32 + lg * 8];
#pragma unroll
    for (int n = 0; n < 4; ++n)
      bfr[n] = *(const s8v*)&Bs[(wc * 64 + n * 16 + lr) * 32 + lg * 8];
#pragma unroll
    for (int m = 0; m < 4; ++m)
#pragma unroll
      for (int n = 0; n < 4; ++n)
        acc[m][n] = mfma16(af[m], bfr[n], acc[m][n]);
  }

  // epilogue: C/D layout col = lane&15, row = (lane>>4)*4 + reg
  if (TRV && blockIdx.z == 2) {
#pragma unroll
    for (int n = 0; n < 4; ++n) {
      const int col = bn * 128 + wc * 64 + n * 16 + lr;
      const float bv = bias[col];
#pragma unroll
      for (int m = 0; m < 4; ++m) {
        const int row0 = bm * 128 + wr * 64 + m * 16 + lg * 4;
        const int bb = row0 >> 11;
        const int s0 = row0 & (SEQ - 1);
        ushort4 pk;
        pk.x = f2b(acc[m][n][0] + bv);
        pk.y = f2b(acc[m][n][1] + bv);
        pk.z = f2b(acc[m][n][2] + bv);
        pk.w = f2b(acc[m][n][3] + bv);
        *(ushort4*)((u16*)Cp + ((size_t)(bb * HID + col)) * SEQ + s0) = pk;
      }
    }
  } else {
#pragma unroll
    for (int n = 0; n < 4; ++n) {
      const int col = bn * 128 + wc * 64 + n * 16 + lr;
      const float bv = bias[col];
#pragma unroll
      for (int m = 0; m < 4; ++m) {
#pragma unroll
        for (int r = 0; r < 4; ++r) {
          const int row = bm * 128 + wr * 64 + m * 16 + lg * 4 + r;
          const float val = acc[m][n][r] + bv;
          if (OUTF32) ((float*)Cp)[(size_t)row * Nsz + col] = val;
          else        ((u16*)Cp)[(size_t)row * Nsz + col] = f2b(val);
        }
      }
    }
  }
}

// ---------------- fused causal attention (barrier-free) ----------------
// grid (4, 2, 32), 256 threads = 4 independent waves (wave w -> head hg*4+w).
// Each wave: 32 q-rows, pairing qt = z and 63-z (uniform 65 tile-units/wave).
// K and V^T fragments read directly from global (L2-resident, 256 KB/head).
__global__ __launch_bounds__(256, 1) void attn_fused(
    const u16* __restrict__ Qm, const u16* __restrict__ Km,
    const u16* __restrict__ Vt, u16* __restrict__ Om)
{
  __shared__ __align__(16) u16 Ps[4 * 32 * PSTR];

  const int hg = blockIdx.x;   // 0..3 head group
  const int b  = blockIdx.y;   // 0..1 batch
  const int pz = blockIdx.z;   // 0..31 qt-pair
  const int t  = threadIdx.x;
  const int w  = t >> 6;
  const int l  = t & 63;
  const int lr = l & 15;
  const int lg = l >> 4;
  const int h  = hg * 4 + w;

  const u16* Qb = Qm + (size_t)(b * SEQ) * HID + h * DH;
  const u16* Kb = Km + (size_t)(b * SEQ) * HID + h * DH;
  const u16* Vb = Vt + (size_t)(b * HID + h * DH) * SEQ;
  u16* Pw = &Ps[w * 32 * PSTR];

  const f4v fzero = {0.f, 0.f, 0.f, 0.f};
  const short ob = (short)0x3F80;          // bf16 1.0
  const s8v ones = {ob, ob, ob, ob, ob, ob, ob, ob};
  const float C = 0.18033688011112042f;    // log2(e) / sqrt(64)

  for (int pi = 0; pi < 2; ++pi) {
    const int qt  = pi ? (SEQ / 32 - 1 - pz) : pz;
    const int qr0 = qt * 32;

    // Q fragments for this wave's 32 rows (2 m-tiles x 2 k-frags)
    s8v aq[2][2];
#pragma unroll
    for (int m = 0; m < 2; ++m)
#pragma unroll
      for (int kk = 0; kk < 2; ++kk)
        aq[m][kk] = *(const s8v*)(Qb + (size_t)(qr0 + m * 16 + lr) * HID + kk * 32 + lg * 8);

    f4v o[2][4];
    float mrow[2][4], lrow[2][4];
#pragma unroll
    for (int m = 0; m < 2; ++m) {
#pragma unroll
      for (int n = 0; n < 4; ++n) o[m][n] = fzero;
#pragma unroll
      for (int r = 0; r < 4; ++r) { mrow[m][r] = -1e30f; lrow[m][r] = 0.f; }
    }

    for (int kt = 0; kt <= qt; ++kt) {
      const int kv0 = kt * 32;

      // K fragments (B-operand, direct global)
      s8v bk[2][2];
#pragma unroll
      for (int n = 0; n < 2; ++n)
#pragma unroll
        for (int kk = 0; kk < 2; ++kk)
          bk[n][kk] = *(const s8v*)(Kb + (size_t)(kv0 + n * 16 + lr) * HID + kk * 32 + lg * 8);
      // V^T fragments (B-operand for PV, direct global, contiguous 16B)
      s8v bv[4];
#pragma unroll
      for (int n = 0; n < 4; ++n)
        bv[n] = *(const s8v*)(Vb + (size_t)(n * 16 + lr) * SEQ + kv0 + lg * 8);

      // S = Q K^T
      f4v s[2][2];
#pragma unroll
      for (int m = 0; m < 2; ++m)
#pragma unroll
        for (int n = 0; n < 2; ++n) {
          f4v a = fzero;
          a = mfma16(aq[m][0], bk[n][0], a);
          a = mfma16(aq[m][1], bk[n][1], a);
          s[m][n] = a;
        }

      // causal mask (only the diagonal tile needs it)
      if (kt == qt) {
#pragma unroll
        for (int m = 0; m < 2; ++m)
#pragma unroll
          for (int n = 0; n < 2; ++n)
#pragma unroll
            for (int r = 0; r < 4; ++r) {
              const int q  = qr0 + m * 16 + lg * 4 + r;
              const int cc = kv0 + n * 16 + lr;
              if (cc > q) s[m][n][r] = -1e30f;
            }
      }

      // row max: reduce over 16 lr-lanes (lg preserved by xor<16)
      float tm[2][4], resc[2][4];
#pragma unroll
      for (int m = 0; m < 2; ++m)
#pragma unroll
        for (int r = 0; r < 4; ++r) tm[m][r] = fmaxf(s[m][0][r], s[m][1][r]);
#pragma unroll
      for (int msk = 1; msk < 16; msk <<= 1)
#pragma unroll
        for (int m = 0; m < 2; ++m)
#pragma unroll
          for (int r = 0; r < 4; ++r)
            tm[m][r] = fmaxf(tm[m][r], __shfl_xor(tm[m][r], msk, 64));

#pragma unroll
      for (int m = 0; m < 2; ++m)
#pragma unroll
        for (int r = 0; r < 4; ++r) {
          const float mn = fmaxf(mrow[m][r], tm[m][r]);
          resc[m][r] = fexp2((mrow[m][r] - mn) * C);
          mrow[m][r] = mn;
        }

      // P = 2^((s-m)*C) -> bf16 -> wave-local LDS (true (q,kv) positions)
#pragma unroll
      for (int m = 0; m < 2; ++m)
#pragma unroll
        for (int r = 0; r < 4; ++r) {
          const float mc = mrow[m][r] * C;
          const float p0 = fexp2(s[m][0][r] * C - mc);
          const float p1 = fexp2(s[m][1][r] * C - mc);
          const int ro = (m * 16 + lg * 4 + r) * PSTR;
          Pw[ro + lr]      = f2b(p0);
          Pw[ro + 16 + lr] = f2b(p1);
        }

      // read back as A-fragment (compiler orders the aliasing LDS ops)
      s8v ap[2];
#pragma unroll
      for (int m = 0; m < 2; ++m)
        ap[m] = *(const s8v*)&Pw[(m * 16 + lr) * PSTR + lg * 8];

      // row-sum via MFMA with ones-vector: rs[m][r] = sum_kv P[row]
      f4v rs[2];
#pragma unroll
      for (int m = 0; m < 2; ++m) rs[m] = mfma16(ap[m], ones, fzero);

#pragma unroll
      for (int m = 0; m < 2; ++m)
#pragma unroll
        for (int r = 0; r < 4; ++r)
          lrow[m][r] = lrow[m][r] * resc[m][r] + rs[m][r];

      // rescale O and accumulate PV
#pragma unroll
      for (int m = 0; m < 2; ++m)
#pragma unroll
        for (int n = 0; n < 4; ++n) {
#pragma unroll
          for (int r = 0; r < 4; ++r) o[m][n][r] *= resc[m][r];
          o[m][n] = mfma16(ap[m], bv[n], o[m][n]);
        }
    }

    // epilogue: normalize and store bf16 att rows
#pragma unroll
    for (int m = 0; m < 2; ++m)
#pragma unroll
      for (int r = 0; r < 4; ++r) {
        const int q = qr0 + m * 16 + lg * 4 + r;
        u16* orow = Om + (size_t)(b * SEQ + q) * HID + h * DH;
        const float inv = 1.0f / lrow[m][r];
#pragma unroll
        for (int n = 0; n < 4; ++n)
          orow[n * 16 + lr] = f2b(o[m][n][r] * inv);
      }
  }
}

// ---------------- launch ----------------
extern "C" void kernel_launch(void* const* d_in, const int* in_sizes, int n_in,
                              void* d_out, int out_size, void* d_ws, size_t ws_size,
                              hipStream_t stream) {
  const float* x  = (const float*)d_in[0];
  const float* Wq = (const float*)d_in[1];
  const float* bq = (const float*)d_in[2];
  const float* Wk = (const float*)d_in[3];
  const float* bk = (const float*)d_in[4];
  const float* Wv = (const float*)d_in[5];
  const float* bv = (const float*)d_in[6];
  const float* Wm = (const float*)d_in[7];
  const float* bm = (const float*)d_in[8];
  float* out = (float*)d_out;

  u16* xb  = (u16*)d_ws;
  u16* Wqb = xb  + (size_t)MROWS * HID;
  u16* Wkb = Wqb + (size_t)HID * HID;
  u16* Wvb = Wkb + (size_t)HID * HID;
  u16* Wmb = Wvb + (size_t)HID * HID;
  u16* Qm  = Wmb + (size_t)HID * HID;
  u16* Km  = Qm  + (size_t)MROWS * HID;
  u16* Vt  = Km  + (size_t)MROWS * HID;   // V stored TRANSPOSED per batch
  u16* att = Vt  + (size_t)MROWS * HID;

  cvt5<<<dim3(512, 5, 1), 256, 0, stream>>>(x, Wq, Wk, Wv, Wm, xb, Wqb, Wkb, Wvb, Wmb);
  gemm_bt<false, true><<<dim3(32, 8, 3), 256, 0, stream>>>(
      xb, Wqb, Wkb, Wvb, bq, bk, bv, Qm, Km, Vt, HID, HID);
  attn_fused<<<dim3(4, 2, 32), 256, 0, stream>>>(Qm, Km, Vt, att);
  gemm_bt<true, false><<<dim3(32, 8, 1), 256, 0, stream>>>(
      att, Wmb, Wmb, Wmb, bm, bm, bm, out, out, out, HID, HID);
}

// Round 3
// 159.126 us; speedup vs baseline: 1.8249x; 1.0681x over previous
//
#include <hip/hip_runtime.h>
#include <hip/hip_bf16.h>
#include <cstdint>
#include <cstddef>

typedef unsigned short u16;
typedef short s8v __attribute__((ext_vector_type(8)));
typedef float f4v __attribute__((ext_vector_type(4)));

#define SEQ   2048
#define BSZ   2
#define HID   1024
#define NH    16
#define DH    64
#define MROWS (BSZ*SEQ)
#define PSTR  40            // P LDS row stride in u16 (80 B)
#define CLOG  0.18033688011112042f   // log2(e)/sqrt(64), folded into Q
#define THR2  6.0f          // defer-max threshold (log2 units): P <= 64

// f32 -> bf16 round-to-nearest-even
__device__ __forceinline__ u16 f2b(float x) {
  union { float f; uint32_t u; } c; c.f = x;
  uint32_t r = (c.u + 0x7fffu + ((c.u >> 16) & 1u)) >> 16;
  return (u16)r;
}

__device__ __forceinline__ f4v mfma16(s8v a, s8v b, f4v c) {
  return __builtin_amdgcn_mfma_f32_16x16x32_bf16(a, b, c, 0, 0, 0);
}

__device__ __forceinline__ float fexp2(float x) {
#if __has_builtin(__builtin_amdgcn_exp2f)
  return __builtin_amdgcn_exp2f(x);
#else
  return exp2f(x);
#endif
}

typedef __attribute__((address_space(1))) const void gas_void;
typedef __attribute__((address_space(3))) void las_void;
__device__ __forceinline__ void gload_lds16(const void* g, void* l) {
  __builtin_amdgcn_global_load_lds((gas_void*)g, (las_void*)l, 16, 0, 0);
}

// ---------------- f32 -> bf16 conversion (5 arrays fused) ----------------
__global__ __launch_bounds__(256) void cvt5(
    const float* __restrict__ s0, const float* __restrict__ s1,
    const float* __restrict__ s2, const float* __restrict__ s3,
    const float* __restrict__ s4,
    u16* __restrict__ d0, u16* __restrict__ d1, u16* __restrict__ d2,
    u16* __restrict__ d3, u16* __restrict__ d4)
{
  const float* s; u16* d; int n;
  switch (blockIdx.y) {
    case 0:  s = s0; d = d0; n = MROWS*HID; break;
    case 1:  s = s1; d = d1; n = HID*HID;   break;
    case 2:  s = s2; d = d2; n = HID*HID;   break;
    case 3:  s = s3; d = d3; n = HID*HID;   break;
    default: s = s4; d = d4; n = HID*HID;   break;
  }
  const int n8 = n >> 3;
  const int stride = gridDim.x * blockDim.x;
  for (int i = blockIdx.x * blockDim.x + threadIdx.x; i < n8; i += stride) {
    const float4* p = (const float4*)s + (size_t)i * 2;
    float4 a = p[0], b = p[1];
    s8v ov;
    ov[0] = (short)f2b(a.x); ov[1] = (short)f2b(a.y);
    ov[2] = (short)f2b(a.z); ov[3] = (short)f2b(a.w);
    ov[4] = (short)f2b(b.x); ov[5] = (short)f2b(b.y);
    ov[6] = (short)f2b(b.z); ov[7] = (short)f2b(b.w);
    ((s8v*)d)[i] = ov;
  }
}

// ---------------- GEMM: C[M,N] = (A[M,K] * B[N,K]^T + bias) * sc ----------------
// 128x128 tile, BK=32, 4 waves, global_load_lds width-16, 16x16x32 bf16 MFMA.
// TRV: blockIdx.z==2 output stored transposed per batch: Vt[(b*HID+col)*SEQ + s]
template <bool OUTF32, bool TRV>
__global__ __launch_bounds__(256) void gemm_bt(
    const u16* __restrict__ A,
    const u16* __restrict__ B0, const u16* __restrict__ B1, const u16* __restrict__ B2,
    const float* __restrict__ bias0, const float* __restrict__ bias1, const float* __restrict__ bias2,
    const float sc0, const float sc1, const float sc2,
    void* C0, void* C1, void* C2,
    const int Ksz, const int Nsz)
{
  const u16* Bp; const float* bias; void* Cp; float sc;
  if (blockIdx.z == 0)      { Bp = B0; bias = bias0; Cp = C0; sc = sc0; }
  else if (blockIdx.z == 1) { Bp = B1; bias = bias1; Cp = C1; sc = sc1; }
  else                      { Bp = B2; bias = bias2; Cp = C2; sc = sc2; }

  __shared__ __align__(16) u16 As[128 * 32];
  __shared__ __align__(16) u16 Bs[128 * 32];

  const int t  = threadIdx.x;
  const int w  = t >> 6;
  const int l  = t & 63;
  const int lr = l & 15;
  const int lg = l >> 4;
  const int wr = w >> 1;
  const int wc = w & 1;

  const int bm = blockIdx.x, bn = blockIdx.y;

  const int srow = t >> 2;
  const int scol = (t & 3) * 8;

  const u16* gA = A  + (size_t)(bm * 128 + srow) * Ksz + scol;
  const u16* gB = Bp + (size_t)(bn * 128 + srow) * Ksz + scol;
  const size_t half = (size_t)64 * Ksz;

  const f4v fzero = {0.f, 0.f, 0.f, 0.f};
  f4v acc[4][4];
#pragma unroll
  for (int m = 0; m < 4; ++m)
#pragma unroll
    for (int n = 0; n < 4; ++n) acc[m][n] = fzero;

  const int nk = Ksz >> 5;
  for (int kt = 0; kt < nk; ++kt) {
    if (kt) __syncthreads();
    gload_lds16(gA,        &As[t * 8]);
    gload_lds16(gA + half, &As[2048 + t * 8]);
    gload_lds16(gB,        &Bs[t * 8]);
    gload_lds16(gB + half, &Bs[2048 + t * 8]);
    gA += 32; gB += 32;
    __syncthreads();

    s8v af[4], bfr[4];
#pragma unroll
    for (int m = 0; m < 4; ++m)
      af[m] = *(const s8v*)&As[(wr * 64 + m * 16 + lr) * 32 + lg * 8];
#pragma unroll
    for (int n = 0; n < 4; ++n)
      bfr[n] = *(const s8v*)&Bs[(wc * 64 + n * 16 + lr) * 32 + lg * 8];
#pragma unroll
    for (int m = 0; m < 4; ++m)
#pragma unroll
      for (int n = 0; n < 4; ++n)
        acc[m][n] = mfma16(af[m], bfr[n], acc[m][n]);
  }

  // epilogue: C/D layout col = lane&15, row = (lane>>4)*4 + reg
  if (TRV && blockIdx.z == 2) {
#pragma unroll
    for (int n = 0; n < 4; ++n) {
      const int col = bn * 128 + wc * 64 + n * 16 + lr;
      const float bv = bias[col];
#pragma unroll
      for (int m = 0; m < 4; ++m) {
        const int row0 = bm * 128 + wr * 64 + m * 16 + lg * 4;
        const int bb = row0 >> 11;
        const int s0 = row0 & (SEQ - 1);
        ushort4 pk;
        pk.x = f2b((acc[m][n][0] + bv) * sc);
        pk.y = f2b((acc[m][n][1] + bv) * sc);
        pk.z = f2b((acc[m][n][2] + bv) * sc);
        pk.w = f2b((acc[m][n][3] + bv) * sc);
        *(ushort4*)((u16*)Cp + ((size_t)(bb * HID + col)) * SEQ + s0) = pk;
      }
    }
  } else {
#pragma unroll
    for (int n = 0; n < 4; ++n) {
      const int col = bn * 128 + wc * 64 + n * 16 + lr;
      const float bv = bias[col];
#pragma unroll
      for (int m = 0; m < 4; ++m) {
#pragma unroll
        for (int r = 0; r < 4; ++r) {
          const int row = bm * 128 + wr * 64 + m * 16 + lg * 4 + r;
          const float val = (acc[m][n][r] + bv) * sc;
          if (OUTF32) ((float*)Cp)[(size_t)row * Nsz + col] = val;
          else        ((u16*)Cp)[(size_t)row * Nsz + col] = f2b(val);
        }
      }
    }
  }
}

// ---------------- fused causal attention (KV-split, flash merge) ----------------
// grid (16, 2, 32): block = (head, batch, qt-pair {pz, 63-pz}).
// 4 waves split KV tiles by kt % 4; per-wave online softmax; LDS merge per qt.
// Q comes in pre-scaled by log2(e)/sqrt(d), so scores are in log2 units.
__global__ __launch_bounds__(256, 4) void attn_fused(
    const u16* __restrict__ Qm, const u16* __restrict__ Km,
    const u16* __restrict__ Vt, u16* __restrict__ Om)
{
  // UnF aliases: per-wave P-transpose slabs (u16) during tiles,
  //              Oacc [4][32][65] f32 during merge.
  __shared__ __align__(16) float UnF[4 * 32 * 65];
  __shared__ float Msh[4][32];
  __shared__ float Lsh[4][32];

  const int h  = blockIdx.x;
  const int b  = blockIdx.y;
  const int pz = blockIdx.z;
  const int t  = threadIdx.x;
  const int w  = t >> 6;
  const int l  = t & 63;
  const int lr = l & 15;
  const int lg = l >> 4;

  const u16* Qb = Qm + (size_t)(b * SEQ) * HID + h * DH;
  const u16* Kb = Km + (size_t)(b * SEQ) * HID + h * DH;
  const u16* Vb = Vt + (size_t)(b * HID + h * DH) * SEQ;
  u16* Pw = (u16*)UnF + w * 32 * PSTR;
  float* Oacc = UnF;

  const f4v fzero = {0.f, 0.f, 0.f, 0.f};
  const short ob = (short)0x3F80;          // bf16 1.0
  const s8v ones = {ob, ob, ob, ob, ob, ob, ob, ob};

  for (int pi = 0; pi < 2; ++pi) {
    const int qt  = pi ? (63 - pz) : pz;
    const int qr0 = qt * 32;

    s8v aq[2][2];
#pragma unroll
    for (int m = 0; m < 2; ++m)
#pragma unroll
      for (int kk = 0; kk < 2; ++kk)
        aq[m][kk] = *(const s8v*)(Qb + (size_t)(qr0 + m * 16 + lr) * HID + kk * 32 + lg * 8);

    f4v o[2][4];
    float mrow[2][4], lrow[2][4];
#pragma unroll
    for (int m = 0; m < 2; ++m) {
#pragma unroll
      for (int n = 0; n < 4; ++n) o[m][n] = fzero;
#pragma unroll
      for (int r = 0; r < 4; ++r) { mrow[m][r] = -1e30f; lrow[m][r] = 0.f; }
    }

    for (int kt = w; kt <= qt; kt += 4) {
      const int kv0 = kt * 32;

      s8v bk[2][2];
#pragma unroll
      for (int n = 0; n < 2; ++n)
#pragma unroll
        for (int kk = 0; kk < 2; ++kk)
          bk[n][kk] = *(const s8v*)(Kb + (size_t)(kv0 + n * 16 + lr) * HID + kk * 32 + lg * 8);
      s8v bv[4];
#pragma unroll
      for (int n = 0; n < 4; ++n)
        bv[n] = *(const s8v*)(Vb + (size_t)(n * 16 + lr) * SEQ + kv0 + lg * 8);

      // S (already in log2 units: Q pre-scaled)
      f4v s[2][2];
#pragma unroll
      for (int m = 0; m < 2; ++m)
#pragma unroll
        for (int n = 0; n < 2; ++n) {
          f4v a = fzero;
          a = mfma16(aq[m][0], bk[n][0], a);
          a = mfma16(aq[m][1], bk[n][1], a);
          s[m][n] = a;
        }

      if (kt == qt) {   // causal mask, diagonal tile only
#pragma unroll
        for (int m = 0; m < 2; ++m)
#pragma unroll
          for (int n = 0; n < 2; ++n)
#pragma unroll
            for (int r = 0; r < 4; ++r) {
              const int q  = qr0 + m * 16 + lg * 4 + r;
              const int cc = kv0 + n * 16 + lr;
              if (cc > q) s[m][n][r] = -1e30f;
            }
      }

      // row max across 16 lr-lanes
      float tm[2][4];
#pragma unroll
      for (int m = 0; m < 2; ++m)
#pragma unroll
        for (int r = 0; r < 4; ++r) tm[m][r] = fmaxf(s[m][0][r], s[m][1][r]);
#pragma unroll
      for (int msk = 1; msk < 16; msk <<= 1)
#pragma unroll
        for (int m = 0; m < 2; ++m)
#pragma unroll
          for (int r = 0; r < 4; ++r)
            tm[m][r] = fmaxf(tm[m][r], __shfl_xor(tm[m][r], msk, 64));

      // defer-max: only rescale when some row's max grew past THR2
      int ok = 1;
#pragma unroll
      for (int m = 0; m < 2; ++m)
#pragma unroll
        for (int r = 0; r < 4; ++r)
          ok &= (tm[m][r] - mrow[m][r] <= THR2) ? 1 : 0;
      if (!__all(ok)) {
#pragma unroll
        for (int m = 0; m < 2; ++m) {
          float resc[4];
#pragma unroll
          for (int r = 0; r < 4; ++r) {
            const float mn = fmaxf(mrow[m][r], tm[m][r]);
            resc[r] = fexp2(mrow[m][r] - mn);
            mrow[m][r] = mn;
            lrow[m][r] *= resc[r];
          }
#pragma unroll
          for (int n = 0; n < 4; ++n)
#pragma unroll
            for (int r = 0; r < 4; ++r) o[m][n][r] *= resc[r];
        }
      }

      // P = 2^(s - m) -> bf16 -> wave-local LDS slab
#pragma unroll
      for (int m = 0; m < 2; ++m)
#pragma unroll
        for (int r = 0; r < 4; ++r) {
          const float p0 = fexp2(s[m][0][r] - mrow[m][r]);
          const float p1 = fexp2(s[m][1][r] - mrow[m][r]);
          const int ro = (m * 16 + lg * 4 + r) * PSTR;
          Pw[ro + lr]      = f2b(p0);
          Pw[ro + 16 + lr] = f2b(p1);
        }
      asm volatile("s_waitcnt lgkmcnt(0)" ::: "memory");
      s8v ap[2];
#pragma unroll
      for (int m = 0; m < 2; ++m)
        ap[m] = *(const s8v*)&Pw[(m * 16 + lr) * PSTR + lg * 8];

      // row-sum via MFMA with ones
      f4v rs[2];
#pragma unroll
      for (int m = 0; m < 2; ++m) rs[m] = mfma16(ap[m], ones, fzero);
#pragma unroll
      for (int m = 0; m < 2; ++m)
#pragma unroll
        for (int r = 0; r < 4; ++r) lrow[m][r] += rs[m][r];

      // PV accumulate
#pragma unroll
      for (int m = 0; m < 2; ++m)
#pragma unroll
        for (int n = 0; n < 4; ++n)
          o[m][n] = mfma16(ap[m], bv[n], o[m][n]);
    }

    // ---- merge the 4 waves' partials (flash combine) ----
    if (lr == 0) {
#pragma unroll
      for (int m = 0; m < 2; ++m)
#pragma unroll
        for (int r = 0; r < 4; ++r) {
          const int row = m * 16 + lg * 4 + r;
          Msh[w][row] = mrow[m][r];
          Lsh[w][row] = lrow[m][r];
        }
    }
    __syncthreads();   // Msh/Lsh visible; all waves past tile loop (P slabs dead)

#pragma unroll
    for (int m = 0; m < 2; ++m)
#pragma unroll
      for (int r = 0; r < 4; ++r) {
        const int row = m * 16 + lg * 4 + r;
        float M = Msh[0][row];
#pragma unroll
        for (int wp = 1; wp < 4; ++wp) M = fmaxf(M, Msh[wp][row]);
        const float f = fexp2(mrow[m][r] - M);
#pragma unroll
        for (int n = 0; n < 4; ++n)
          Oacc[((size_t)(w * 32 + row)) * 65 + n * 16 + lr] = o[m][n][r] * f;
      }
    __syncthreads();   // Oacc complete

    // sum phase: wave w handles rows w*8 .. w*8+7, lane l = column
#pragma unroll
    for (int j = 0; j < 8; ++j) {
      const int row = w * 8 + j;
      float M = Msh[0][row];
#pragma unroll
      for (int wp = 1; wp < 4; ++wp) M = fmaxf(M, Msh[wp][row]);
      float lt = 0.f;
#pragma unroll
      for (int wp = 0; wp < 4; ++wp) lt += fexp2(Msh[wp][row] - M) * Lsh[wp][row];
      float v = 0.f;
#pragma unroll
      for (int wp = 0; wp < 4; ++wp) v += Oacc[((size_t)(wp * 32 + row)) * 65 + l];
      const int q = qr0 + row;
      Om[(size_t)(b * SEQ + q) * HID + h * DH + l] = f2b(v / lt);
    }
    __syncthreads();   // protect UnF before next pi's P writes
  }
}

// ---------------- launch ----------------
extern "C" void kernel_launch(void* const* d_in, const int* in_sizes, int n_in,
                              void* d_out, int out_size, void* d_ws, size_t ws_size,
                              hipStream_t stream) {
  const float* x  = (const float*)d_in[0];
  const float* Wq = (const float*)d_in[1];
  const float* bq = (const float*)d_in[2];
  const float* Wk = (const float*)d_in[3];
  const float* bk = (const float*)d_in[4];
  const float* Wv = (const float*)d_in[5];
  const float* bv = (const float*)d_in[6];
  const float* Wm = (const float*)d_in[7];
  const float* bm = (const float*)d_in[8];
  float* out = (float*)d_out;

  u16* xb  = (u16*)d_ws;
  u16* Wqb = xb  + (size_t)MROWS * HID;
  u16* Wkb = Wqb + (size_t)HID * HID;
  u16* Wvb = Wkb + (size_t)HID * HID;
  u16* Wmb = Wvb + (size_t)HID * HID;
  u16* Qm  = Wmb + (size_t)HID * HID;
  u16* Km  = Qm  + (size_t)MROWS * HID;
  u16* Vt  = Km  + (size_t)MROWS * HID;   // V stored transposed per batch
  u16* att = Vt  + (size_t)MROWS * HID;

  cvt5<<<dim3(512, 5, 1), 256, 0, stream>>>(x, Wq, Wk, Wv, Wm, xb, Wqb, Wkb, Wvb, Wmb);
  gemm_bt<false, true><<<dim3(32, 8, 3), 256, 0, stream>>>(
      xb, Wqb, Wkb, Wvb, bq, bk, bv, CLOG, 1.f, 1.f, Qm, Km, Vt, HID, HID);
  attn_fused<<<dim3(16, 2, 32), 256, 0, stream>>>(Qm, Km, Vt, att);
  gemm_bt<true, false><<<dim3(32, 8, 1), 256, 0, stream>>>(
      att, Wmb, Wmb, Wmb, bm, bm, bm, 1.f, 1.f, 1.f, out, out, out, HID, HID);
}

// Round 5
// 148.673 us; speedup vs baseline: 1.9532x; 1.0703x over previous
//
#include <hip/hip_runtime.h>
#include <hip/hip_bf16.h>
#include <cstdint>
#include <cstddef>

typedef unsigned short u16;
typedef short s8v __attribute__((ext_vector_type(8)));
typedef float f4v __attribute__((ext_vector_type(4)));
typedef float f16v __attribute__((ext_vector_type(16)));

#define SEQ   2048
#define BSZ   2
#define HID   1024
#define NH    16
#define DH    64
#define MROWS (BSZ*SEQ)
#define CLOG  0.18033688011112042f   // log2(e)/sqrt(64), folded into Q
#define THR2  6.0f                   // defer-max threshold (log2 units): P <= 64

// f32 -> bf16 round-to-nearest-even
__device__ __forceinline__ u16 f2b(float x) {
  union { float f; uint32_t u; } c; c.f = x;
  uint32_t r = (c.u + 0x7fffu + ((c.u >> 16) & 1u)) >> 16;
  return (u16)r;
}

__device__ __forceinline__ f4v mfma16(s8v a, s8v b, f4v c) {
  return __builtin_amdgcn_mfma_f32_16x16x32_bf16(a, b, c, 0, 0, 0);
}
__device__ __forceinline__ f16v mfma32(s8v a, s8v b, f16v c) {
  return __builtin_amdgcn_mfma_f32_32x32x16_bf16(a, b, c, 0, 0, 0);
}

__device__ __forceinline__ float fexp2(float x) {
#if __has_builtin(__builtin_amdgcn_exp2f)
  return __builtin_amdgcn_exp2f(x);
#else
  return exp2f(x);
#endif
}

// pack 2 f32 -> bf16x2 (lo = a, hi = b)
__device__ __forceinline__ uint32_t pkbf16(float a, float b) {
  uint32_t d;
  asm("v_cvt_pk_bf16_f32 %0, %1, %2" : "=v"(d) : "v"(a), "v"(b));
  return d;
}
// v_permlane32_swap_b32 dst,src: new dst = {dst.lo31, src.lo31},
//                                new src = {dst.hi31, src.hi31}
__device__ __forceinline__ void pswap(uint32_t& x, uint32_t& y) {
  asm("v_permlane32_swap_b32 %0, %1" : "+v"(x), "+v"(y));
}

typedef __attribute__((address_space(1))) const void gas_void;
typedef __attribute__((address_space(3))) void las_void;
__device__ __forceinline__ void gload_lds16(const void* g, void* l) {
  __builtin_amdgcn_global_load_lds((gas_void*)g, (las_void*)l, 16, 0, 0);
}

// ---------------- f32 -> bf16 conversion (5 arrays fused) ----------------
__global__ __launch_bounds__(256) void cvt5(
    const float* __restrict__ s0, const float* __restrict__ s1,
    const float* __restrict__ s2, const float* __restrict__ s3,
    const float* __restrict__ s4,
    u16* __restrict__ d0, u16* __restrict__ d1, u16* __restrict__ d2,
    u16* __restrict__ d3, u16* __restrict__ d4)
{
  const float* s; u16* d; int n;
  switch (blockIdx.y) {
    case 0:  s = s0; d = d0; n = MROWS*HID; break;
    case 1:  s = s1; d = d1; n = HID*HID;   break;
    case 2:  s = s2; d = d2; n = HID*HID;   break;
    case 3:  s = s3; d = d3; n = HID*HID;   break;
    default: s = s4; d = d4; n = HID*HID;   break;
  }
  const int n8 = n >> 3;
  const int stride = gridDim.x * blockDim.x;
  for (int i = blockIdx.x * blockDim.x + threadIdx.x; i < n8; i += stride) {
    const float4* p = (const float4*)s + (size_t)i * 2;
    float4 a = p[0], b = p[1];
    s8v ov;
    ov[0] = (short)f2b(a.x); ov[1] = (short)f2b(a.y);
    ov[2] = (short)f2b(a.z); ov[3] = (short)f2b(a.w);
    ov[4] = (short)f2b(b.x); ov[5] = (short)f2b(b.y);
    ov[6] = (short)f2b(b.z); ov[7] = (short)f2b(b.w);
    ((s8v*)d)[i] = ov;
  }
}

// ---------------- GEMM: C[M,N] = (A[M,K] * B[N,K]^T + bias) * sc ----------------
template <bool OUTF32, bool TRV>
__global__ __launch_bounds__(256) void gemm_bt(
    const u16* __restrict__ A,
    const u16* __restrict__ B0, const u16* __restrict__ B1, const u16* __restrict__ B2,
    const float* __restrict__ bias0, const float* __restrict__ bias1, const float* __restrict__ bias2,
    const float sc0, const float sc1, const float sc2,
    void* C0, void* C1, void* C2,
    const int Ksz, const int Nsz)
{
  const u16* Bp; const float* bias; void* Cp; float sc;
  if (blockIdx.z == 0)      { Bp = B0; bias = bias0; Cp = C0; sc = sc0; }
  else if (blockIdx.z == 1) { Bp = B1; bias = bias1; Cp = C1; sc = sc1; }
  else                      { Bp = B2; bias = bias2; Cp = C2; sc = sc2; }

  __shared__ __align__(16) u16 As[128 * 32];
  __shared__ __align__(16) u16 Bs[128 * 32];

  const int t  = threadIdx.x;
  const int w  = t >> 6;
  const int l  = t & 63;
  const int lr = l & 15;
  const int lg = l >> 4;
  const int wr = w >> 1;
  const int wc = w & 1;

  const int bm = blockIdx.x, bn = blockIdx.y;

  const int srow = t >> 2;
  const int scol = (t & 3) * 8;

  const u16* gA = A  + (size_t)(bm * 128 + srow) * Ksz + scol;
  const u16* gB = Bp + (size_t)(bn * 128 + srow) * Ksz + scol;
  const size_t half = (size_t)64 * Ksz;

  const f4v fzero = {0.f, 0.f, 0.f, 0.f};
  f4v acc[4][4];
#pragma unroll
  for (int m = 0; m < 4; ++m)
#pragma unroll
    for (int n = 0; n < 4; ++n) acc[m][n] = fzero;

  const int nk = Ksz >> 5;
  for (int kt = 0; kt < nk; ++kt) {
    if (kt) __syncthreads();
    gload_lds16(gA,        &As[t * 8]);
    gload_lds16(gA + half, &As[2048 + t * 8]);
    gload_lds16(gB,        &Bs[t * 8]);
    gload_lds16(gB + half, &Bs[2048 + t * 8]);
    gA += 32; gB += 32;
    __syncthreads();

    s8v af[4], bfr[4];
#pragma unroll
    for (int m = 0; m < 4; ++m)
      af[m] = *(const s8v*)&As[(wr * 64 + m * 16 + lr) * 32 + lg * 8];
#pragma unroll
    for (int n = 0; n < 4; ++n)
      bfr[n] = *(const s8v*)&Bs[(wc * 64 + n * 16 + lr) * 32 + lg * 8];
#pragma unroll
    for (int m = 0; m < 4; ++m)
#pragma unroll
      for (int n = 0; n < 4; ++n)
        acc[m][n] = mfma16(af[m], bfr[n], acc[m][n]);
  }

  if (TRV && blockIdx.z == 2) {
#pragma unroll
    for (int n = 0; n < 4; ++n) {
      const int col = bn * 128 + wc * 64 + n * 16 + lr;
      const float bv = bias[col];
#pragma unroll
      for (int m = 0; m < 4; ++m) {
        const int row0 = bm * 128 + wr * 64 + m * 16 + lg * 4;
        const int bb = row0 >> 11;
        const int s0 = row0 & (SEQ - 1);
        ushort4 pk;
        pk.x = f2b((acc[m][n][0] + bv) * sc);
        pk.y = f2b((acc[m][n][1] + bv) * sc);
        pk.z = f2b((acc[m][n][2] + bv) * sc);
        pk.w = f2b((acc[m][n][3] + bv) * sc);
        *(ushort4*)((u16*)Cp + ((size_t)(bb * HID + col)) * SEQ + s0) = pk;
      }
    }
  } else {
#pragma unroll
    for (int n = 0; n < 4; ++n) {
      const int col = bn * 128 + wc * 64 + n * 16 + lr;
      const float bv = bias[col];
#pragma unroll
      for (int m = 0; m < 4; ++m) {
#pragma unroll
        for (int r = 0; r < 4; ++r) {
          const int row = bm * 128 + wr * 64 + m * 16 + lg * 4 + r;
          const float val = (acc[m][n][r] + bv) * sc;
          if (OUTF32) ((float*)Cp)[(size_t)row * Nsz + col] = val;
          else        ((u16*)Cp)[(size_t)row * Nsz + col] = f2b(val);
        }
      }
    }
  }
}

// ---------------- fused causal attention (swapped QK^T, 32x32 MFMA) ----------------
// grid (16, 2, 32): block = (head, batch, qt-pair {pz, 63-pz}).
// 4 waves split KV tiles by kt % 4; lane-local softmax (T12); flash merge per qt.
// Q pre-scaled by log2(e)/sqrt(d); scores in log2 units.
// S^T = mfma(A=K, B=Q): lane l holds S[q = l&31, kv = (r&3)+8*(r>>2)+4*(l>>5)].
__global__ __launch_bounds__(256, 4) void attn_fused(
    const u16* __restrict__ Qm, const u16* __restrict__ Km,
    const u16* __restrict__ Vt, u16* __restrict__ Om)
{
  __shared__ __align__(16) float Oacc[128 * 65];
  __shared__ float Msh[4][32];
  __shared__ float Lsh[4][32];
  __shared__ float Rsh[4][32];

  const int h  = blockIdx.x;
  const int b  = blockIdx.y;
  const int pz = blockIdx.z;
  const int t  = threadIdx.x;
  const int w  = t >> 6;
  const int l  = t & 63;
  const int l31 = l & 31;
  const int hi  = l >> 5;
  const int hi8 = hi * 8;
  const int hi4 = hi * 4;

  const u16* Qb = Qm + (size_t)(b * SEQ) * HID + h * DH;
  const u16* Kb = Km + (size_t)(b * SEQ) * HID + h * DH;
  const u16* Vb = Vt + (size_t)(b * HID + h * DH) * SEQ;

  const f16v z16 = {0.f,0.f,0.f,0.f,0.f,0.f,0.f,0.f,0.f,0.f,0.f,0.f,0.f,0.f,0.f,0.f};

  for (int pi = 0; pi < 2; ++pi) {
    const int qt  = pi ? (63 - pz) : pz;
    const int qr0 = qt * 32;

    // Q fragments (B-operand): lane -> col q = l31, k = d
    const u16* qrow = Qb + (size_t)(qr0 + l31) * HID + hi8;
    const s8v q0 = *(const s8v*)(qrow);
    const s8v q1 = *(const s8v*)(qrow + 16);
    const s8v q2 = *(const s8v*)(qrow + 32);
    const s8v q3 = *(const s8v*)(qrow + 48);

    f16v o0 = z16, o1 = z16;
    float mrow = -1e30f, lrow = 0.f;

    for (int kt = w; kt <= qt; kt += 4) {
      const int kv0 = kt * 32;

      // K fragments (A-operand): lane -> row kv = kv0 + l31, k = d
      const u16* krow = Kb + (size_t)(kv0 + l31) * HID + hi8;
      const s8v ak0 = *(const s8v*)(krow);
      const s8v ak1 = *(const s8v*)(krow + 16);
      const s8v ak2 = *(const s8v*)(krow + 32);
      const s8v ak3 = *(const s8v*)(krow + 48);
      // V^T fragments (B-operand for PV): lane -> col d = dt*32 + l31, k = kv
      const u16* vc0 = Vb + (size_t)l31 * SEQ + kv0 + hi8;
      const u16* vc1 = vc0 + (size_t)32 * SEQ;
      const s8v bv00 = *(const s8v*)(vc0);        // kv 0..15,  d-tile 0
      const s8v bv10 = *(const s8v*)(vc0 + 16);   // kv 16..31, d-tile 0
      const s8v bv01 = *(const s8v*)(vc1);
      const s8v bv11 = *(const s8v*)(vc1 + 16);

      // S^T tile
      f16v st = z16;
      st = mfma32(ak0, q0, st);
      st = mfma32(ak1, q1, st);
      st = mfma32(ak2, q2, st);
      st = mfma32(ak3, q3, st);

      if (kt == qt) {   // causal mask, diagonal tile only (kv0 == qr0)
#pragma unroll
        for (int r = 0; r < 16; ++r)
          if (((r & 3) + 8 * (r >> 2) + hi4) > l31) st[r] = -1e30f;
      }

      // row max: in-register tree + cross-half swap
      float a0 = fmaxf(st[0], st[8]),  a1 = fmaxf(st[1], st[9]);
      float a2 = fmaxf(st[2], st[10]), a3 = fmaxf(st[3], st[11]);
      float a4 = fmaxf(st[4], st[12]), a5 = fmaxf(st[5], st[13]);
      float a6 = fmaxf(st[6], st[14]), a7 = fmaxf(st[7], st[15]);
      float b0 = fmaxf(a0, a4), b1 = fmaxf(a1, a5), b2 = fmaxf(a2, a6), b3 = fmaxf(a3, a7);
      float tm = fmaxf(fmaxf(b0, b1), fmaxf(b2, b3));
      tm = fmaxf(tm, __shfl_xor(tm, 32, 64));

      // defer-max: rescale only when some row's max grew past THR2
      if (!__all((tm - mrow <= THR2) ? 1 : 0)) {
        const float mn = fmaxf(mrow, tm);
        const float rs = fexp2(mrow - mn);
        mrow = mn;
        lrow *= rs;
        if (l < 32) Rsh[w][l31] = rs;
#pragma unroll
        for (int r = 0; r < 16; ++r) {
          const float f = Rsh[w][(r & 3) + 8 * (r >> 2) + hi4];
          o0[r] *= f; o1[r] *= f;
        }
      }

      // P = 2^(s - m), lane-local
      float p[16];
#pragma unroll
      for (int r = 0; r < 16; ++r) p[r] = fexp2(st[r] - mrow);

      // row sum: tree + cross-half swap
      float u0 = p[0]+p[8],  u1 = p[1]+p[9],  u2 = p[2]+p[10], u3 = p[3]+p[11];
      float u4 = p[4]+p[12], u5 = p[5]+p[13], u6 = p[6]+p[14], u7 = p[7]+p[15];
      float v0 = u0+u4, v1 = u1+u5, v2 = u2+u6, v3 = u3+u7;
      float ts = (v0+v1) + (v2+v3);
      ts += __shfl_xor(ts, 32, 64);
      lrow += ts;

      // P -> bf16 A-fragments via cvt_pk + permlane32_swap (m214 recipe).
      // pswap(X, Y): X <- {X.lo31, Y.lo31} (= word j), Y <- {X.hi31, Y.hi31} (= word j+2)
      uint32_t A0 = pkbf16(p[0], p[1]),  A1 = pkbf16(p[2], p[3]);
      uint32_t B0 = pkbf16(p[4], p[5]),  B1 = pkbf16(p[6], p[7]);
      pswap(A0, B0); pswap(A1, B1);
      uint32_t C0 = pkbf16(p[8], p[9]),  C1 = pkbf16(p[10], p[11]);
      uint32_t D0 = pkbf16(p[12], p[13]), D1 = pkbf16(p[14], p[15]);
      pswap(C0, D0); pswap(C1, D1);
      union { uint32_t wd[4]; s8v v; } f0, f1;
      f0.wd[0] = A0; f0.wd[1] = A1; f0.wd[2] = B0; f0.wd[3] = B1;   // kv 0..15
      f1.wd[0] = C0; f1.wd[1] = C1; f1.wd[2] = D0; f1.wd[3] = D1;   // kv 16..31

      // O += P V
      o0 = mfma32(f0.v, bv00, o0);
      o0 = mfma32(f1.v, bv10, o0);
      o1 = mfma32(f0.v, bv01, o1);
      o1 = mfma32(f1.v, bv11, o1);
    }

    // ---- flash merge of the 4 waves' partials ----
    if (l < 32) { Msh[w][l31] = mrow; Lsh[w][l31] = lrow; }
    __syncthreads();

    float fr[16];
#pragma unroll
    for (int r = 0; r < 16; ++r) {
      const int q = (r & 3) + 8 * (r >> 2) + hi4;
      float M = fmaxf(fmaxf(Msh[0][q], Msh[1][q]), fmaxf(Msh[2][q], Msh[3][q]));
      fr[r] = fexp2(Msh[w][q] - M);
    }
#pragma unroll
    for (int r = 0; r < 16; ++r) {
      const int q = (r & 3) + 8 * (r >> 2) + hi4;
      Oacc[(w * 32 + q) * 65 + l31]      = o0[r] * fr[r];
      Oacc[(w * 32 + q) * 65 + 32 + l31] = o1[r] * fr[r];
    }
    __syncthreads();

    // sum phase: wave w -> rows w*8..w*8+7, lane l -> column d
#pragma unroll
    for (int j = 0; j < 8; ++j) {
      const int row = w * 8 + j;
      float M = fmaxf(fmaxf(Msh[0][row], Msh[1][row]), fmaxf(Msh[2][row], Msh[3][row]));
      float lt = 0.f;
#pragma unroll
      for (int wp = 0; wp < 4; ++wp) lt += fexp2(Msh[wp][row] - M) * Lsh[wp][row];
      float v = 0.f;
#pragma unroll
      for (int wp = 0; wp < 4; ++wp) v += Oacc[(wp * 32 + row) * 65 + l];
      Om[(size_t)(b * SEQ + qr0 + row) * HID + h * DH + l] = f2b(v / lt);
    }
    __syncthreads();
  }
}

// ---------------- launch ----------------
extern "C" void kernel_launch(void* const* d_in, const int* in_sizes, int n_in,
                              void* d_out, int out_size, void* d_ws, size_t ws_size,
                              hipStream_t stream) {
  const float* x  = (const float*)d_in[0];
  const float* Wq = (const float*)d_in[1];
  const float* bq = (const float*)d_in[2];
  const float* Wk = (const float*)d_in[3];
  const float* bk = (const float*)d_in[4];
  const float* Wv = (const float*)d_in[5];
  const float* bv = (const float*)d_in[6];
  const float* Wm = (const float*)d_in[7];
  const float* bm = (const float*)d_in[8];
  float* out = (float*)d_out;

  u16* xb  = (u16*)d_ws;
  u16* Wqb = xb  + (size_t)MROWS * HID;
  u16* Wkb = Wqb + (size_t)HID * HID;
  u16* Wvb = Wkb + (size_t)HID * HID;
  u16* Wmb = Wvb + (size_t)HID * HID;
  u16* Qm  = Wmb + (size_t)HID * HID;
  u16* Km  = Qm  + (size_t)MROWS * HID;
  u16* Vt  = Km  + (size_t)MROWS * HID;   // V stored transposed per batch
  u16* att = Vt  + (size_t)MROWS * HID;

  cvt5<<<dim3(512, 5, 1), 256, 0, stream>>>(x, Wq, Wk, Wv, Wm, xb, Wqb, Wkb, Wvb, Wmb);
  gemm_bt<false, true><<<dim3(32, 8, 3), 256, 0, stream>>>(
      xb, Wqb, Wkb, Wvb, bq, bk, bv, CLOG, 1.f, 1.f, Qm, Km, Vt, HID, HID);
  attn_fused<<<dim3(16, 2, 32), 256, 0, stream>>>(Qm, Km, Vt, att);
  gemm_bt<true, false><<<dim3(32, 8, 1), 256, 0, stream>>>(
      att, Wmb, Wmb, Wmb, bm, bm, bm, 1.f, 1.f, 1.f, out, out, out, HID, HID);
}